// Round 4
// baseline (27.529 us; speedup 1.0000x reference)
//
#include <hip/hip_runtime.h>

// loss = -1.5 * SSQ + Q + 0.5 * TT
//   S_c = sum of feat rows with label c; SSQ = sum_c |S_c|^2
//   T   = sum of all rows; TT = |T|^2;  Q = sum feat^2
//
// Class-major decomposition:
//  K0 (1 block): bucket row indices by class (LDS atomics), zero accumulators.
//  K1 (200 blocks = class x dim-half): gather own rows, register-accumulate
//     S_c half; atomicAdd into T / ssq / q; last block (flag) computes the
//     final scalar with agent-scope atomic loads (bypass stale per-XCD L2).

constexpr int B_MAX = 8192;
constexpr int D     = 256;
constexpr int NC    = 100;
constexpr int STR   = 160;   // list stride per class (mean 82, +8.7 sigma)

__global__ __launch_bounds__(1024) void k_bucket(
    const int* __restrict__ label, int* __restrict__ list,
    int* __restrict__ cnt, float* __restrict__ T,
    float* __restrict__ scal, unsigned int* __restrict__ flag, int B) {
  __shared__ int lcnt[NC];
  const int tid = threadIdx.x;
  if (tid < NC) lcnt[tid] = 0;
  __syncthreads();
  for (int r = tid; r < B; r += 1024) {
    const int c = label[r];
    const int p = atomicAdd(&lcnt[c], 1);
    if (p < STR) list[c * STR + p] = r;
  }
  __syncthreads();
  if (tid < NC) cnt[tid] = min(lcnt[tid], STR);
  if (tid < D) T[tid] = 0.f;
  if (tid == D)     { scal[0] = 0.f; scal[1] = 0.f; }
  if (tid == D + 1) { *flag = 0u; }
}

__global__ __launch_bounds__(128) void k_gather(
    const float* __restrict__ feat, const int* __restrict__ list,
    const int* __restrict__ cnt, float* __restrict__ T,
    float* __restrict__ scal, unsigned int* __restrict__ flag,
    float* __restrict__ out) {
  const int c  = blockIdx.x >> 1;
  const int dh = blockIdx.x & 1;
  const int t  = threadIdx.x;
  __shared__ int   lidx[STR];
  __shared__ float red[128];
  __shared__ unsigned int lastv;

  const int n = cnt[c];
  for (int i = t; i < n; i += 128) lidx[i] = list[c * STR + i];
  __syncthreads();

  const float* fb = feat + dh * 128 + t;
  float S = 0.f, q = 0.f;
  #pragma unroll 4
  for (int i = 0; i < n; ++i) {
    const float v = fb[(size_t)lidx[i] * D];
    S += v;
    q += v * v;
  }

  atomicAdd(&T[dh * 128 + t], S);

  red[t] = S * S;
  __syncthreads();
  #pragma unroll
  for (int s = 64; s > 0; s >>= 1) {
    if (t < s) red[t] += red[t + s];
    __syncthreads();
  }
  if (t == 0) atomicAdd(&scal[0], red[0]);
  __syncthreads();
  red[t] = q;
  __syncthreads();
  #pragma unroll
  for (int s = 64; s > 0; s >>= 1) {
    if (t < s) red[t] += red[t + s];
    __syncthreads();
  }
  if (t == 0) atomicAdd(&scal[1], red[0]);

  __threadfence();
  if (t == 0) lastv = atomicAdd(flag, 1u);
  __syncthreads();

  if (lastv == 2 * NC - 1) {           // last block: finish
    __threadfence();
    float ttp = 0.f;
    for (int d = t; d < D; d += 128) {
      const float tv = __hip_atomic_load(&T[d], __ATOMIC_RELAXED,
                                         __HIP_MEMORY_SCOPE_AGENT);
      ttp += tv * tv;
    }
    red[t] = ttp;
    __syncthreads();
    #pragma unroll
    for (int s = 64; s > 0; s >>= 1) {
      if (t < s) red[t] += red[t + s];
      __syncthreads();
    }
    if (t == 0) {
      const float ssq = __hip_atomic_load(&scal[0], __ATOMIC_RELAXED,
                                          __HIP_MEMORY_SCOPE_AGENT);
      const float qq  = __hip_atomic_load(&scal[1], __ATOMIC_RELAXED,
                                          __HIP_MEMORY_SCOPE_AGENT);
      out[0] = -1.5f * ssq + qq + 0.5f * red[0];
    }
  }
}

extern "C" void kernel_launch(void* const* d_in, const int* in_sizes, int n_in,
                              void* d_out, int out_size, void* d_ws, size_t ws_size,
                              hipStream_t stream) {
  (void)n_in; (void)out_size; (void)ws_size;
  const float* feat  = (const float*)d_in[0];
  const int*   label = (const int*)d_in[1];
  const int B = in_sizes[1];

  int*   list = (int*)d_ws;                 // NC*STR
  int*   cnt  = list + NC * STR;            // NC
  float* T    = (float*)(cnt + NC);         // D
  float* scal = T + D;                      // ssq, q
  unsigned int* flag = (unsigned int*)(scal + 2);

  k_bucket<<<1, 1024, 0, stream>>>(label, list, cnt, T, scal, flag, B);
  k_gather<<<2 * NC, 128, 0, stream>>>(feat, list, cnt, T, scal, flag,
                                       (float*)d_out);
}

// Round 5
// 20.157 us; speedup vs baseline: 1.3658x; 1.3658x over previous
//
#include <hip/hip_runtime.h>

// loss = -1.5 * SSQ + Q + 0.5 * TT
//   S_c = sum of feat rows with label c; SSQ = sum_c |S_c|^2
//   T = sum of all rows; TT = |T|^2; Q = sum feat^2
//
// K1: 100 blocks (one per class) x 256 threads (thread = dim).
//     Each block scans all labels (int4), builds its own row list in LDS
//     (rare atomic pushes, ~82/block), register-gathers S_c and q partial,
//     plain-stores S_c row + q partial to ws. No global atomics.
// K2: 1 block x 256 threads: one pass over the 100x256 S table gives
//     T_d (per-dim), SSQ (sum S^2); reduce TT = sum T_d^2; sum q partials.
// Cross-kernel visibility via kernel-boundary coherence (validated R1/R3).

constexpr int D   = 256;
constexpr int NC  = 100;
constexpr int STR = 256;            // row-list capacity (mean 82, ~19 sigma)
// ws layout (floats)
constexpr size_t SOFF = 0;                     // S table [NC][D]
constexpr size_t QOFF = (size_t)NC * D;        // q partials [NC]

__global__ __launch_bounds__(256) void k_classgather(
    const float* __restrict__ feat, const int* __restrict__ label,
    float* __restrict__ ws, int B) {
  __shared__ int   lidx[STR];
  __shared__ int   lcnt;
  __shared__ float red[256];
  const int c = blockIdx.x;
  const int t = threadIdx.x;

  if (t == 0) lcnt = 0;
  __syncthreads();

  // scan labels, push matching row indices (order irrelevant)
  const int4* lab4 = (const int4*)label;
  const int nvec = B >> 2;
  for (int v = t; v < nvec; v += 256) {
    const int4 L = lab4[v];
    const int r = 4 * v;
    if (L.x == c) { int p = atomicAdd(&lcnt, 1); if (p < STR) lidx[p] = r; }
    if (L.y == c) { int p = atomicAdd(&lcnt, 1); if (p < STR) lidx[p] = r + 1; }
    if (L.z == c) { int p = atomicAdd(&lcnt, 1); if (p < STR) lidx[p] = r + 2; }
    if (L.w == c) { int p = atomicAdd(&lcnt, 1); if (p < STR) lidx[p] = r + 3; }
  }
  __syncthreads();
  const int n = min(lcnt, STR);

  // gather: register accumulation, independent pipelined loads
  const float* fb = feat + t;
  float S = 0.f, q = 0.f;
  #pragma unroll 8
  for (int i = 0; i < n; ++i) {
    const float v = fb[(size_t)lidx[i] * D];
    S += v;
    q += v * v;
  }

  ws[SOFF + (size_t)c * D + t] = S;

  red[t] = q;
  __syncthreads();
  #pragma unroll
  for (int s = 128; s > 0; s >>= 1) {
    if (t < s) red[t] += red[t + s];
    __syncthreads();
  }
  if (t == 0) ws[QOFF + c] = red[0];
}

__global__ __launch_bounds__(256) void k_finish(
    const float* __restrict__ ws, float* __restrict__ out) {
  const int t = threadIdx.x;        // owns dim t
  float T = 0.f, ssq = 0.f;
  #pragma unroll 10
  for (int c = 0; c < NC; ++c) {
    const float v = ws[SOFF + (size_t)c * D + t];
    T   += v;
    ssq += v * v;
  }
  const float q = (t < NC) ? ws[QOFF + t] : 0.f;

  __shared__ float red[256];
  red[t] = T * T;
  __syncthreads();
  #pragma unroll
  for (int s = 128; s > 0; s >>= 1) { if (t < s) red[t] += red[t + s]; __syncthreads(); }
  const float TT = red[0];
  __syncthreads();
  red[t] = ssq;
  __syncthreads();
  #pragma unroll
  for (int s = 128; s > 0; s >>= 1) { if (t < s) red[t] += red[t + s]; __syncthreads(); }
  const float SSQ = red[0];
  __syncthreads();
  red[t] = q;
  __syncthreads();
  #pragma unroll
  for (int s = 128; s > 0; s >>= 1) { if (t < s) red[t] += red[t + s]; __syncthreads(); }
  if (t == 0) out[0] = -1.5f * SSQ + red[0] + 0.5f * TT;
}

extern "C" void kernel_launch(void* const* d_in, const int* in_sizes, int n_in,
                              void* d_out, int out_size, void* d_ws, size_t ws_size,
                              hipStream_t stream) {
  (void)n_in; (void)out_size; (void)ws_size;
  const float* feat  = (const float*)d_in[0];
  const int*   label = (const int*)d_in[1];
  float*       ws    = (float*)d_ws;
  const int B = in_sizes[1];

  k_classgather<<<NC, 256, 0, stream>>>(feat, label, ws, B);
  k_finish<<<1, 256, 0, stream>>>(ws, (float*)d_out);
}

// Round 6
// 14.997 us; speedup vs baseline: 1.8356x; 1.3440x over previous
//
#include <hip/hip_runtime.h>

// loss = -1.5 * SSQ + Q + 0.5 * TT
//   S_c = sum of feat rows with label c; SSQ = sum_c |S_c|^2
//   T = sum of all rows; TT = |T|^2; Q = sum feat^2
//
// K1: 100 blocks (one per class) x 1024 threads (4 list-parity slices x 256
//     dims). Scan labels (int4, 2/thread), build row list in LDS, 4-way
//     split register gather (~21 loads/thread), combine via LDS, plain-store
//     S_c row + q partial. No global atomics.
// K2: 1 block x 256 threads, float4 pass over S table -> T4 partials, SSQ;
//     LDS combine -> TT, SSQ, Q -> out.

constexpr int D   = 256;
constexpr int NC  = 100;
constexpr int STR = 256;            // row-list capacity (mean 82, ~19 sigma)
constexpr size_t QOFF = (size_t)NC * D;   // q partials after S table

__global__ __launch_bounds__(1024) void k_classgather(
    const float* __restrict__ feat, const int* __restrict__ label,
    float* __restrict__ ws, int B) {
  __shared__ int   lidx[STR];
  __shared__ int   lcnt;
  __shared__ float psum[4 * D];
  __shared__ float qred[1024];
  const int c = blockIdx.x;
  const int t = threadIdx.x;
  const int p = t >> 8;             // list-parity slice 0..3
  const int d = t & 255;            // dim

  if (t == 0) lcnt = 0;
  __syncthreads();

  const int4* lab4 = (const int4*)label;
  const int nvec = B >> 2;          // 2048
  for (int v = t; v < nvec; v += 1024) {
    const int4 L = lab4[v];
    const int r = 4 * v;
    if (L.x == c) { int i = atomicAdd(&lcnt, 1); if (i < STR) lidx[i] = r; }
    if (L.y == c) { int i = atomicAdd(&lcnt, 1); if (i < STR) lidx[i] = r + 1; }
    if (L.z == c) { int i = atomicAdd(&lcnt, 1); if (i < STR) lidx[i] = r + 2; }
    if (L.w == c) { int i = atomicAdd(&lcnt, 1); if (i < STR) lidx[i] = r + 3; }
  }
  __syncthreads();
  const int n = min(lcnt, STR);

  const float* fb = feat + d;
  float S = 0.f, q = 0.f;
  #pragma unroll 4
  for (int i = p; i < n; i += 4) {   // ~21 independent loads, 256B/wave
    const float v = fb[(size_t)lidx[i] * D];
    S += v;
    q += v * v;
  }
  psum[p * D + d] = S;
  qred[t] = q;
  __syncthreads();

  if (t < D)
    ws[(size_t)c * D + t] =
        psum[t] + psum[D + t] + psum[2 * D + t] + psum[3 * D + t];

  #pragma unroll
  for (int s = 512; s > 0; s >>= 1) {
    if (t < s) qred[t] += qred[t + s];
    __syncthreads();
  }
  if (t == 0) ws[QOFF + c] = qred[0];
}

__global__ __launch_bounds__(256) void k_finish(
    const float* __restrict__ ws, float* __restrict__ out) {
  const int t   = threadIdx.x;
  const int rg  = t >> 6;           // row group 0..3
  const int col = t & 63;           // float4 column
  const float4* S4 = (const float4*)ws;   // [NC][64]
  float4 T = make_float4(0.f, 0.f, 0.f, 0.f);
  float ssq = 0.f;
  #pragma unroll 5
  for (int k = 0; k < 25; ++k) {
    const float4 v = S4[(size_t)(rg + 4 * k) * 64 + col];
    T.x += v.x; T.y += v.y; T.z += v.z; T.w += v.w;
    ssq += v.x * v.x + v.y * v.y + v.z * v.z + v.w * v.w;
  }
  __shared__ float4 sh4[256];
  __shared__ float  red[256];
  sh4[t] = T;
  red[t] = ssq;
  __syncthreads();
  #pragma unroll
  for (int s = 128; s > 0; s >>= 1) {
    if (t < s) red[t] += red[t + s];
    __syncthreads();
  }
  const float SSQ = red[0];
  __syncthreads();

  float ttp = 0.f;
  if (t < 64) {
    const float4 a = sh4[t], b = sh4[64 + t], c = sh4[128 + t], e = sh4[192 + t];
    const float tx = a.x + b.x + c.x + e.x;
    const float ty = a.y + b.y + c.y + e.y;
    const float tz = a.z + b.z + c.z + e.z;
    const float tw = a.w + b.w + c.w + e.w;
    ttp = tx * tx + ty * ty + tz * tz + tw * tw;
  }
  red[t] = ttp;
  __syncthreads();
  #pragma unroll
  for (int s = 128; s > 0; s >>= 1) {
    if (t < s) red[t] += red[t + s];
    __syncthreads();
  }
  const float TT = red[0];
  __syncthreads();

  red[t] = (t < NC) ? ws[QOFF + t] : 0.f;
  __syncthreads();
  #pragma unroll
  for (int s = 128; s > 0; s >>= 1) {
    if (t < s) red[t] += red[t + s];
    __syncthreads();
  }
  if (t == 0) out[0] = -1.5f * SSQ + red[0] + 0.5f * TT;
}

extern "C" void kernel_launch(void* const* d_in, const int* in_sizes, int n_in,
                              void* d_out, int out_size, void* d_ws, size_t ws_size,
                              hipStream_t stream) {
  (void)n_in; (void)out_size; (void)ws_size;
  const float* feat  = (const float*)d_in[0];
  const int*   label = (const int*)d_in[1];
  float*       ws    = (float*)d_ws;
  const int B = in_sizes[1];

  k_classgather<<<NC, 1024, 0, stream>>>(feat, label, ws, B);
  k_finish<<<1, 256, 0, stream>>>(ws, (float*)d_out);
}

// Round 7
// 14.702 us; speedup vs baseline: 1.8724x; 1.0201x over previous
//
#include <hip/hip_runtime.h>

// loss = -1.5 * SSQ + Q + 0.5 * TT
//   S_c = sum of feat rows with label c; SSQ = sum_c |S_c|^2
//   T = sum of all rows; TT = |T|^2; Q = sum feat^2
//
// K1: 200 blocks (class x dim-half) x 1024 threads (8 list-parity slices x
//     128 dims). Scan labels (int4, 2/thread), build row list in LDS,
//     8-way split register gather (~10 loads/thread, 256B/wave coalesced),
//     combine via LDS; q via wave shuffles (no barrier tree).
// K2: 1 block x 256 threads, float4 pass over S table -> TT, SSQ, Q -> out.

constexpr int D   = 256;
constexpr int NC  = 100;
constexpr int STR = 256;                  // row-list capacity (mean 82)
constexpr size_t QOFF = (size_t)NC * D;   // q partials [200] after S table

__global__ __launch_bounds__(1024) void k_classgather(
    const float* __restrict__ feat, const int* __restrict__ label,
    float* __restrict__ ws, int B) {
  __shared__ int   lidx[STR];
  __shared__ int   lcnt;
  __shared__ float psum[8 * 128];
  __shared__ float qw[16];
  const int bid = blockIdx.x;
  const int c   = bid >> 1;
  const int dh  = bid & 1;
  const int t   = threadIdx.x;
  const int p   = t >> 7;                 // list-parity slice 0..7
  const int d   = t & 127;                // dim within half

  if (t == 0) lcnt = 0;
  __syncthreads();

  const int4* lab4 = (const int4*)label;
  const int nvec = B >> 2;                // 2048
  for (int v = t; v < nvec; v += 1024) {
    const int4 L = lab4[v];
    const int r = 4 * v;
    if (L.x == c) { int i = atomicAdd(&lcnt, 1); if (i < STR) lidx[i] = r; }
    if (L.y == c) { int i = atomicAdd(&lcnt, 1); if (i < STR) lidx[i] = r + 1; }
    if (L.z == c) { int i = atomicAdd(&lcnt, 1); if (i < STR) lidx[i] = r + 2; }
    if (L.w == c) { int i = atomicAdd(&lcnt, 1); if (i < STR) lidx[i] = r + 3; }
  }
  __syncthreads();
  const int n = min(lcnt, STR);

  const float* fb = feat + dh * 128 + d;
  float S = 0.f, q = 0.f;
  #pragma unroll 4
  for (int i = p; i < n; i += 8) {        // ~10 independent loads
    const float v = fb[(size_t)lidx[i] * D];
    S += v;
    q += v * v;
  }
  psum[p * 128 + d] = S;

  // q: wave shuffle reduce (no barriers), then fold 16 wave partials
  #pragma unroll
  for (int o = 32; o > 0; o >>= 1) q += __shfl_down(q, o);
  if ((t & 63) == 0) qw[t >> 6] = q;
  __syncthreads();

  if (t < 128) {
    float s = 0.f;
    #pragma unroll
    for (int k = 0; k < 8; ++k) s += psum[k * 128 + t];
    ws[(size_t)c * D + dh * 128 + t] = s;
  }
  if (t < 64) {
    float v = (t < 16) ? qw[t] : 0.f;
    #pragma unroll
    for (int o = 8; o > 0; o >>= 1) v += __shfl_down(v, o);
    if (t == 0) ws[QOFF + bid] = v;
  }
}

__global__ __launch_bounds__(256) void k_finish(
    const float* __restrict__ ws, float* __restrict__ out) {
  const int t   = threadIdx.x;
  const int rg  = t >> 6;                 // row group 0..3
  const int col = t & 63;                 // float4 column
  const float4* S4 = (const float4*)ws;   // [NC][64]
  float4 T = make_float4(0.f, 0.f, 0.f, 0.f);
  float ssq = 0.f;
  #pragma unroll 5
  for (int k = 0; k < 25; ++k) {
    const float4 v = S4[(size_t)(rg + 4 * k) * 64 + col];
    T.x += v.x; T.y += v.y; T.z += v.z; T.w += v.w;
    ssq += v.x * v.x + v.y * v.y + v.z * v.z + v.w * v.w;
  }
  __shared__ float4 sh4[256];
  __shared__ float  red[256];
  sh4[t] = T;
  red[t] = ssq;
  __syncthreads();
  #pragma unroll
  for (int s = 128; s > 0; s >>= 1) {
    if (t < s) red[t] += red[t + s];
    __syncthreads();
  }
  const float SSQ = red[0];
  __syncthreads();

  float ttp = 0.f;
  if (t < 64) {
    const float4 a = sh4[t], b = sh4[64 + t], c = sh4[128 + t], e = sh4[192 + t];
    const float tx = a.x + b.x + c.x + e.x;
    const float ty = a.y + b.y + c.y + e.y;
    const float tz = a.z + b.z + c.z + e.z;
    const float tw = a.w + b.w + c.w + e.w;
    ttp = tx * tx + ty * ty + tz * tz + tw * tw;
  }
  red[t] = ttp;
  __syncthreads();
  #pragma unroll
  for (int s = 128; s > 0; s >>= 1) {
    if (t < s) red[t] += red[t + s];
    __syncthreads();
  }
  const float TT = red[0];
  __syncthreads();

  red[t] = (t < 2 * NC) ? ws[QOFF + t] : 0.f;
  __syncthreads();
  #pragma unroll
  for (int s = 128; s > 0; s >>= 1) {
    if (t < s) red[t] += red[t + s];
    __syncthreads();
  }
  if (t == 0) out[0] = -1.5f * SSQ + red[0] + 0.5f * TT;
}

extern "C" void kernel_launch(void* const* d_in, const int* in_sizes, int n_in,
                              void* d_out, int out_size, void* d_ws, size_t ws_size,
                              hipStream_t stream) {
  (void)n_in; (void)out_size; (void)ws_size;
  const float* feat  = (const float*)d_in[0];
  const int*   label = (const int*)d_in[1];
  float*       ws    = (float*)d_ws;
  const int B = in_sizes[1];

  k_classgather<<<2 * NC, 1024, 0, stream>>>(feat, label, ws, B);
  k_finish<<<1, 256, 0, stream>>>(ws, (float*)d_out);
}